// Round 1
// baseline (2897.876 us; speedup 1.0000x reference)
//
#include <hip/hip_runtime.h>

// ---------------------------------------------------------------------------
// Gemma3 prefill forward, MI355X (gfx950).
// Shapes: L=12 D=1152 NH=4 NG=1 HD=256 F=6912 V=32768 T=128 C=1920 S=2048
// Strategy: bf16 MFMA GEMMs streaming fp32 weights (memory-bound),
// flash attention with analytic masks, fp32 residual stream.
// ---------------------------------------------------------------------------

using f4  = __attribute__((ext_vector_type(4))) float;
using s8v = __attribute__((ext_vector_type(8))) short;

__device__ inline short f2bf(float f) {
  union { float f; unsigned u; } v; v.f = f;
  unsigned r = v.u + 0x7fffu + ((v.u >> 16) & 1u);
  return (short)(r >> 16);
}
__device__ inline float bf2f(short s) {
  union { unsigned u; float f; } v; v.u = ((unsigned)(unsigned short)s) << 16;
  return v.f;
}

constexpr int   Dm  = 1152;
constexpr int   HD  = 256;
constexpr int   Fm  = 6912;
constexpr int   Vv  = 32768;
constexpr int   Tm  = 128;
constexpr int   Cm  = 1920;
constexpr float LOG2E = 1.4426950408889634f;
// 2*scale/(CAP*ln2), scale=1/16, CAP=50
constexpr float K_TANH = 0.003606737602222409f;

// ---------------------------------------------------------------------------
// Generic GEMM: out[ns][128][N] (bf16 or fp32) = A(128xK bf16) @ B(KxN fp32)
// BN=64, wave w -> mtiles {2w,2w+1} x 4 ntiles. Split-K over blockIdx.y.
// ---------------------------------------------------------------------------
template<int BN, int WM, int WN, int NSPLIT, bool OUT_BF16>
__global__ __launch_bounds__(256) void gemm_bf16(
    const short* __restrict__ A, const float* __restrict__ B,
    void* __restrict__ outv, int K, int N)
{
  constexpr int NT  = BN / 16;
  constexpr int MG  = 8 / WM;
  constexpr int NGR = NT / WN;
  static_assert(MG * NGR == 4, "4 waves");
  const int nblk = blockIdx.x;
  const int ks   = blockIdx.y;
  const int Kc   = K / NSPLIT;
  const int kbeg = ks * Kc;
  const int tid  = threadIdx.x;
  const int w = tid >> 6, l = tid & 63;
  const int lane16 = l & 15, quad = l >> 4;
  const int mg = w % MG, ng = w / MG;
  const int m_base = mg * (WM * 16);
  const int n_base = nblk * BN + ng * (WN * 16);

  f4 acc[WM][WN];
  #pragma unroll
  for (int i = 0; i < WM; i++)
    #pragma unroll
    for (int j = 0; j < WN; j++) { f4 z = {0.f,0.f,0.f,0.f}; acc[i][j] = z; }

  for (int k0 = kbeg; k0 < kbeg + Kc; k0 += 32) {
    s8v a[WM];
    #pragma unroll
    for (int mt = 0; mt < WM; mt++)
      a[mt] = *(const s8v*)(A + (size_t)(m_base + mt*16 + lane16) * K + k0 + quad*8);
    s8v b[WN];
    #pragma unroll
    for (int nt = 0; nt < WN; nt++) {
      const float* bp = B + (size_t)(k0 + quad*8) * N + (n_base + nt*16 + lane16);
      s8v t;
      #pragma unroll
      for (int j = 0; j < 8; j++) t[j] = f2bf(bp[(size_t)j * N]);
      b[nt] = t;
    }
    #pragma unroll
    for (int mt = 0; mt < WM; mt++)
      #pragma unroll
      for (int nt = 0; nt < WN; nt++)
        acc[mt][nt] = __builtin_amdgcn_mfma_f32_16x16x32_bf16(a[mt], b[nt], acc[mt][nt], 0, 0, 0);
  }

  if constexpr (OUT_BF16) {
    short* out = (short*)outv + (size_t)ks * 128 * N;
    #pragma unroll
    for (int mt = 0; mt < WM; mt++)
      #pragma unroll
      for (int nt = 0; nt < WN; nt++)
        #pragma unroll
        for (int r = 0; r < 4; r++)
          out[(size_t)(m_base + mt*16 + quad*4 + r) * N + n_base + nt*16 + lane16] =
              f2bf(acc[mt][nt][r]);
  } else {
    float* out = (float*)outv + (size_t)ks * 128 * N;
    #pragma unroll
    for (int mt = 0; mt < WM; mt++)
      #pragma unroll
      for (int nt = 0; nt < WN; nt++)
        #pragma unroll
        for (int r = 0; r < 4; r++)
          out[(size_t)(m_base + mt*16 + quad*4 + r) * N + n_base + nt*16 + lane16] =
              acc[mt][nt][r];
  }
}

// ---------------------------------------------------------------------------
// Fused gate/up GEMM + tanh-GELU * up epilogue -> ff bf16 [128][6912]
// BN=32, wave: mg=w&1 (64 rows), ng=w>>1 (16 cols), both weight matrices.
// ---------------------------------------------------------------------------
__global__ __launch_bounds__(256) void gemm_gateup(
    const short* __restrict__ A, const float* __restrict__ Bg,
    const float* __restrict__ Bu, short* __restrict__ ff)
{
  const int nblk = blockIdx.x;
  const int tid  = threadIdx.x;
  const int w = tid >> 6, l = tid & 63;
  const int lane16 = l & 15, quad = l >> 4;
  const int mg = w & 1, ng = w >> 1;
  const int m_base = mg * 64;
  const int n_col  = nblk * 32 + ng * 16 + lane16;

  f4 accg[4], accu[4];
  #pragma unroll
  for (int i = 0; i < 4; i++) { f4 z = {0.f,0.f,0.f,0.f}; accg[i] = z; accu[i] = z; }

  for (int k0 = 0; k0 < Dm; k0 += 32) {
    s8v a[4];
    #pragma unroll
    for (int mt = 0; mt < 4; mt++)
      a[mt] = *(const s8v*)(A + (size_t)(m_base + mt*16 + lane16) * Dm + k0 + quad*8);
    const float* bpg = Bg + (size_t)(k0 + quad*8) * Fm + n_col;
    const float* bpu = Bu + (size_t)(k0 + quad*8) * Fm + n_col;
    s8v bg, bu;
    #pragma unroll
    for (int j = 0; j < 8; j++) { bg[j] = f2bf(bpg[(size_t)j * Fm]); bu[j] = f2bf(bpu[(size_t)j * Fm]); }
    #pragma unroll
    for (int mt = 0; mt < 4; mt++) {
      accg[mt] = __builtin_amdgcn_mfma_f32_16x16x32_bf16(a[mt], bg, accg[mt], 0, 0, 0);
      accu[mt] = __builtin_amdgcn_mfma_f32_16x16x32_bf16(a[mt], bu, accu[mt], 0, 0, 0);
    }
  }
  #pragma unroll
  for (int mt = 0; mt < 4; mt++)
    #pragma unroll
    for (int r = 0; r < 4; r++) {
      int rowi = m_base + mt*16 + quad*4 + r;
      float g = accg[mt][r], u = accu[mt][r];
      float y = 0.7978845608f * (g + 0.044715f * g * g * g);
      float sg = 1.f / (1.f + exp2f(y * -2.885390082f));   // sigmoid(2y)
      ff[(size_t)rowi * Fm + n_col] = f2bf(g * sg * u);
    }
}

// ---------------------------------------------------------------------------
// qkv epilogue: sum 6 bf16 split-K slices, per-head q RMS+RoPE -> qa bf16,
// k RMS+RoPE -> d_out k-slice (fp32), v -> d_out v-slice transposed.
// One block per token t.
// ---------------------------------------------------------------------------
__global__ __launch_bounds__(256) void qkv_prep(
    const short* __restrict__ qkv_part,   // [6][128][1536]
    const float* __restrict__ qnw, const float* __restrict__ knw,
    const float* __restrict__ cosb, const float* __restrict__ sinb, // [128][256]
    short* __restrict__ qa,               // [4][128][256]
    float* __restrict__ kout,             // [128][256] (d_out)
    float* __restrict__ vout)             // [256][128] (d_out)
{
  const int t = blockIdx.x;
  const int tid = threadIdx.x;
  __shared__ float row[1536];
  __shared__ float invs[5];
  for (int j = tid; j < 1536; j += 256) {
    float s = 0.f;
    #pragma unroll
    for (int c = 0; c < 6; c++)
      s += bf2f(qkv_part[(size_t)c * 128 * 1536 + (size_t)t * 1536 + j]);
    row[j] = s;
  }
  __syncthreads();
  const int w = tid >> 6, l = tid & 63;
  {
    float ps = 0.f;
    #pragma unroll
    for (int jj = 0; jj < 4; jj++) { float x = row[w*256 + jj*64 + l]; ps += x * x; }
    #pragma unroll
    for (int d = 1; d < 64; d <<= 1) ps += __shfl_xor(ps, d);
    if (l == 0) invs[w] = rsqrtf(ps * (1.f/256.f) + 1e-6f);
    if (w == 0) {
      float pk = 0.f;
      #pragma unroll
      for (int jj = 0; jj < 4; jj++) { float x = row[1024 + jj*64 + l]; pk += x * x; }
      #pragma unroll
      for (int d = 1; d < 64; d <<= 1) pk += __shfl_xor(pk, d);
      if (l == 0) invs[4] = rsqrtf(pk * (1.f/256.f) + 1e-6f);
    }
  }
  __syncthreads();
  {
    float inv = invs[w];
    #pragma unroll
    for (int jj = 0; jj < 2; jj++) {
      int d = jj*64 + l;                       // 0..127
      float x1 = row[w*256 + d]       * inv * (1.f + qnw[d]);
      float x2 = row[w*256 + d + 128] * inv * (1.f + qnw[d + 128]);
      float c1 = cosb[t*256 + d],       s1 = sinb[t*256 + d];
      float c2 = cosb[t*256 + d + 128], s2 = sinb[t*256 + d + 128];
      qa[(size_t)(w*128 + t)*256 + d]       = f2bf(x1 * c1 - x2 * s1);
      qa[(size_t)(w*128 + t)*256 + d + 128] = f2bf(x2 * c2 + x1 * s2);
    }
  }
  if (w == 1) {
    float inv = invs[4];
    #pragma unroll
    for (int jj = 0; jj < 2; jj++) {
      int d = jj*64 + l;
      float x1 = row[1024 + d]       * inv * (1.f + knw[d]);
      float x2 = row[1024 + d + 128] * inv * (1.f + knw[d + 128]);
      float c1 = cosb[t*256 + d],       s1 = sinb[t*256 + d];
      float c2 = cosb[t*256 + d + 128], s2 = sinb[t*256 + d + 128];
      kout[t*256 + d]       = x1 * c1 - x2 * s1;
      kout[t*256 + d + 128] = x2 * c2 + x1 * s2;
    }
  }
  if (w >= 2) {
    #pragma unroll
    for (int jj = 0; jj < 2; jj++) {
      int d = (w - 2)*128 + jj*64 + l;
      vout[(size_t)d * 128 + t] = row[1280 + d];
    }
  }
}

// ---------------------------------------------------------------------------
// Flash attention partial: block = (chunk 0..7, qtile 0..1, head 0..3).
// Scores 64x256 via MFMA, softcap tanh + analytic mask, online m/l,
// P->LDS(bf16)->PV MFMA. Writes m,l (fp32) and O (bf16) partials.
// ---------------------------------------------------------------------------
__global__ __launch_bounds__(256) void flash_partial(
    const short* __restrict__ qa,
    const float* __restrict__ kcache, const float* __restrict__ knew,
    const float* __restrict__ vcache, const float* __restrict__ vnew,
    float* __restrict__ m_part, float* __restrict__ l_part,
    short* __restrict__ o_part, int is_local)
{
  const int chunk = blockIdx.x, qt = blockIdx.y, h = blockIdx.z;
  const int tid = threadIdx.x;
  const int w = tid >> 6, l = tid & 63;
  const int lane16 = l & 15, quad = l >> 4;
  const int n0w = w * 64;
  const int t_base = qt * 64;
  const int s_base = chunk * 256;

  __shared__ __align__(16) short P[64 * 264];
  __shared__ float red[256];

  f4 acc[4][4];
  #pragma unroll
  for (int i = 0; i < 4; i++)
    #pragma unroll
    for (int j = 0; j < 4; j++) { f4 z = {0.f,0.f,0.f,0.f}; acc[i][j] = z; }

  // ---- QK^T ----
  for (int kk = 0; kk < 8; kk++) {
    int k0 = kk * 32;
    s8v a[4];
    #pragma unroll
    for (int mt = 0; mt < 4; mt++)
      a[mt] = *(const s8v*)(qa + (size_t)(h*128 + t_base + mt*16 + lane16)*256 + k0 + quad*8);
    s8v b[4];
    #pragma unroll
    for (int nt = 0; nt < 4; nt++) {
      int sg = s_base + n0w + nt*16 + lane16;
      const float* kp = (sg < Cm) ? (kcache + (size_t)sg * 256)
                                  : (knew + (size_t)(sg - Cm) * 256);
      f4 f0 = *(const f4*)(kp + k0 + quad*8);
      f4 f1 = *(const f4*)(kp + k0 + quad*8 + 4);
      s8v t;
      #pragma unroll
      for (int j = 0; j < 4; j++) { t[j] = f2bf(f0[j]); t[4+j] = f2bf(f1[j]); }
      b[nt] = t;
    }
    #pragma unroll
    for (int mt = 0; mt < 4; mt++)
      #pragma unroll
      for (int nt = 0; nt < 4; nt++)
        acc[mt][nt] = __builtin_amdgcn_mfma_f32_16x16x32_bf16(a[mt], b[nt], acc[mt][nt], 0, 0, 0);
  }

  // ---- softcap + mask + row max ----
  int srel[4];
  #pragma unroll
  for (int nt = 0; nt < 4; nt++) srel[nt] = s_base + n0w + nt*16 + lane16 - Cm;
  float mrow[4][4];
  #pragma unroll
  for (int mt = 0; mt < 4; mt++)
    #pragma unroll
    for (int r = 0; r < 4; r++) {
      int trow = t_base + mt*16 + quad*4 + r;
      float mx = -3.4e38f;
      #pragma unroll
      for (int nt = 0; nt < 4; nt++) {
        float sc = acc[mt][nt][r];
        float e = exp2f(sc * K_TANH);
        float capped = 50.f - 100.f / (e + 1.f);
        bool ok = (srel[nt] <= trow) && (!is_local || (srel[nt] > trow - 1024));
        float vv = ok ? capped : (capped - 1e9f);
        acc[mt][nt][r] = vv;
        mx = fmaxf(mx, vv);
      }
      mrow[mt][r] = mx;
    }
  #pragma unroll
  for (int mt = 0; mt < 4; mt++)
    #pragma unroll
    for (int r = 0; r < 4; r++) {
      float m = mrow[mt][r];
      m = fmaxf(m, __shfl_xor(m, 1)); m = fmaxf(m, __shfl_xor(m, 2));
      m = fmaxf(m, __shfl_xor(m, 4)); m = fmaxf(m, __shfl_xor(m, 8));
      mrow[mt][r] = m;
    }
  if (lane16 == 0)
    #pragma unroll
    for (int mt = 0; mt < 4; mt++)
      #pragma unroll
      for (int r = 0; r < 4; r++) red[w*64 + mt*16 + quad*4 + r] = mrow[mt][r];
  __syncthreads();
  #pragma unroll
  for (int mt = 0; mt < 4; mt++)
    #pragma unroll
    for (int r = 0; r < 4; r++) {
      int rr = mt*16 + quad*4 + r;
      mrow[mt][r] = fmaxf(fmaxf(red[rr], red[64 + rr]), fmaxf(red[128 + rr], red[192 + rr]));
    }
  // ---- exp + row sum ----
  float lrow[4][4];
  #pragma unroll
  for (int mt = 0; mt < 4; mt++)
    #pragma unroll
    for (int r = 0; r < 4; r++) {
      float s = 0.f;
      #pragma unroll
      for (int nt = 0; nt < 4; nt++) {
        float p = exp2f((acc[mt][nt][r] - mrow[mt][r]) * LOG2E);
        acc[mt][nt][r] = p;
        s += p;
      }
      s += __shfl_xor(s, 1); s += __shfl_xor(s, 2);
      s += __shfl_xor(s, 4); s += __shfl_xor(s, 8);
      lrow[mt][r] = s;
    }
  __syncthreads();
  if (lane16 == 0)
    #pragma unroll
    for (int mt = 0; mt < 4; mt++)
      #pragma unroll
      for (int r = 0; r < 4; r++) red[w*64 + mt*16 + quad*4 + r] = lrow[mt][r];
  __syncthreads();
  if (w == 0 && lane16 == 0) {
    int base = ((h*2 + qt)*8 + chunk) * 64;
    #pragma unroll
    for (int mt = 0; mt < 4; mt++)
      #pragma unroll
      for (int r = 0; r < 4; r++) {
        int rr = mt*16 + quad*4 + r;
        m_part[base + rr] = mrow[mt][r];
        l_part[base + rr] = red[rr] + red[64 + rr] + red[128 + rr] + red[192 + rr];
      }
  }
  // ---- P -> LDS bf16 ----
  #pragma unroll
  for (int mt = 0; mt < 4; mt++)
    #pragma unroll
    for (int nt = 0; nt < 4; nt++)
      #pragma unroll
      for (int r = 0; r < 4; r++)
        P[(mt*16 + quad*4 + r)*264 + n0w + nt*16 + lane16] = f2bf(acc[mt][nt][r]);
  __syncthreads();

  // ---- P @ V ----
  f4 oacc[4][4];
  #pragma unroll
  for (int i = 0; i < 4; i++)
    #pragma unroll
    for (int j = 0; j < 4; j++) { f4 z = {0.f,0.f,0.f,0.f}; oacc[i][j] = z; }
  for (int kk = 0; kk < 8; kk++) {
    int k0 = kk * 32;
    s8v a[4];
    #pragma unroll
    for (int mt = 0; mt < 4; mt++)
      a[mt] = *(const s8v*)(&P[(mt*16 + lane16)*264 + k0 + quad*8]);
    s8v b[4];
    int s0 = s_base + k0 + quad*8;
    #pragma unroll
    for (int nt = 0; nt < 4; nt++) {
      int d = n0w + nt*16 + lane16;
      const float* vp = (s0 < Cm) ? (vcache + (size_t)d * Cm + s0)
                                  : (vnew + (size_t)d * 128 + (s0 - Cm));
      f4 f0 = *(const f4*)vp;
      f4 f1 = *(const f4*)(vp + 4);
      s8v t;
      #pragma unroll
      for (int j = 0; j < 4; j++) { t[j] = f2bf(f0[j]); t[4+j] = f2bf(f1[j]); }
      b[nt] = t;
    }
    #pragma unroll
    for (int mt = 0; mt < 4; mt++)
      #pragma unroll
      for (int nt = 0; nt < 4; nt++)
        oacc[mt][nt] = __builtin_amdgcn_mfma_f32_16x16x32_bf16(a[mt], b[nt], oacc[mt][nt], 0, 0, 0);
  }
  short* ob = o_part + (size_t)(((h*2 + qt)*8 + chunk) * 64) * 256;
  #pragma unroll
  for (int mt = 0; mt < 4; mt++)
    #pragma unroll
    for (int nt = 0; nt < 4; nt++)
      #pragma unroll
      for (int r = 0; r < 4; r++)
        ob[(size_t)(mt*16 + quad*4 + r)*256 + n0w + nt*16 + lane16] = f2bf(oacc[mt][nt][r]);
}

// ---------------------------------------------------------------------------
// Combine 8 chunk partials -> ao bf16 [128][1024] (= out.transpose reshaped)
// ---------------------------------------------------------------------------
__global__ __launch_bounds__(256) void attn_combine(
    const float* __restrict__ m_part, const float* __restrict__ l_part,
    const short* __restrict__ o_part, short* __restrict__ ao)
{
  const int qt = blockIdx.x, h = blockIdx.y;
  const int tid = threadIdx.x;
  const int row = tid >> 2, di = tid & 3;
  const int base = ((h*2 + qt)*8) * 64;
  float mc[8], we[8];
  float M = -3.4e38f;
  #pragma unroll
  for (int c = 0; c < 8; c++) { mc[c] = m_part[base + c*64 + row]; M = fmaxf(M, mc[c]); }
  float den = 0.f;
  #pragma unroll
  for (int c = 0; c < 8; c++) {
    we[c] = exp2f((mc[c] - M) * LOG2E);
    den += we[c] * l_part[base + c*64 + row];
  }
  float invd = 1.f / den;
  const short* ob = o_part + (size_t)base * 256;
  for (int i = 0; i < 64; i++) {
    int d = di + i*4;
    float o = 0.f;
    #pragma unroll
    for (int c = 0; c < 8; c++)
      o += we[c] * bf2f(ob[(size_t)(c*64 + row)*256 + d]);
    ao[(size_t)(qt*64 + row)*1024 + h*256 + d] = f2bf(o * invd);
  }
}

// ---------------------------------------------------------------------------
// Residual epilogue: sum NS bf16 split-K slices -> p; h += rms(p,w1);
// xb = bf16(rms(h,w2)). One block per token.
// ---------------------------------------------------------------------------
__device__ inline float block_sum256(float v, float* red4) {
  #pragma unroll
  for (int d = 1; d < 64; d <<= 1) v += __shfl_xor(v, d);
  int w = threadIdx.x >> 6;
  if ((threadIdx.x & 63) == 0) red4[w] = v;
  __syncthreads();
  float s = red4[0] + red4[1] + red4[2] + red4[3];
  __syncthreads();
  return s;
}

template<int NS>
__global__ __launch_bounds__(256) void resid_norm(
    const short* __restrict__ part, const float* __restrict__ w1,
    float* __restrict__ h, const float* __restrict__ w2, short* __restrict__ xb)
{
  const int t = blockIdx.x, tid = threadIdx.x;
  __shared__ float red4[4];
  float pv[5]; float ssq = 0.f;
  #pragma unroll
  for (int k = 0; k < 5; k++) {
    int j = tid + k*256; pv[k] = 0.f;
    if (j < Dm) {
      float s = 0.f;
      #pragma unroll
      for (int c = 0; c < NS; c++)
        s += bf2f(part[(size_t)c * 128 * Dm + (size_t)t * Dm + j]);
      pv[k] = s; ssq += s * s;
    }
  }
  float tot = block_sum256(ssq, red4);
  float inv = rsqrtf(tot * (1.f / Dm) + 1e-6f);
  float hv[5]; float ssq2 = 0.f;
  #pragma unroll
  for (int k = 0; k < 5; k++) {
    int j = tid + k*256; hv[k] = 0.f;
    if (j < Dm) {
      float hn = h[(size_t)t * Dm + j] + pv[k] * inv * (1.f + w1[j]);
      h[(size_t)t * Dm + j] = hn;
      hv[k] = hn; ssq2 += hn * hn;
    }
  }
  float tot2 = block_sum256(ssq2, red4);
  float inv2 = rsqrtf(tot2 * (1.f / Dm) + 1e-6f);
  #pragma unroll
  for (int k = 0; k < 5; k++) {
    int j = tid + k*256;
    if (j < Dm) xb[(size_t)t * Dm + j] = f2bf(hv[k] * inv2 * (1.f + w2[j]));
  }
}

__global__ __launch_bounds__(256) void init_h(
    const float* __restrict__ emb, const float* __restrict__ w0,
    float* __restrict__ h, short* __restrict__ xb)
{
  const int t = blockIdx.x, tid = threadIdx.x;
  __shared__ float red4[4];
  float pv[5]; float ssq = 0.f;
  #pragma unroll
  for (int k = 0; k < 5; k++) {
    int j = tid + k*256; pv[k] = 0.f;
    if (j < Dm) { float v = emb[(size_t)t * Dm + j]; h[(size_t)t * Dm + j] = v; pv[k] = v; ssq += v * v; }
  }
  float tot = block_sum256(ssq, red4);
  float inv = rsqrtf(tot * (1.f / Dm) + 1e-6f);
  #pragma unroll
  for (int k = 0; k < 5; k++) {
    int j = tid + k*256;
    if (j < Dm) xb[(size_t)t * Dm + j] = f2bf(pv[k] * inv * (1.f + w0[j]));
  }
}

// ---------------------------------------------------------------------------
extern "C" void kernel_launch(void* const* d_in, const int* in_sizes, int n_in,
                              void* d_out, int out_size, void* d_ws, size_t ws_size,
                              hipStream_t stream) {
  const float* emb      = (const float*)d_in[0];
  const float* pe_cos   = (const float*)d_in[3];
  const float* pe_sin   = (const float*)d_in[4];
  const float* pe_cosl  = (const float*)d_in[5];
  const float* pe_sinl  = (const float*)d_in[6];
  const float* kv_k     = (const float*)d_in[7];
  const float* kv_v     = (const float*)d_in[8];
  const float* pre_attn = (const float*)d_in[9];
  const float* q_norm   = (const float*)d_in[10];
  const float* k_norm   = (const float*)d_in[11];
  const float* post_attn= (const float*)d_in[12];
  const float* pre_ff   = (const float*)d_in[13];
  const float* post_ff  = (const float*)d_in[14];
  const float* final_w  = (const float*)d_in[15];
  const float* w_qkv    = (const float*)d_in[16];
  const float* w_out    = (const float*)d_in[17];
  const float* w_gate   = (const float*)d_in[18];
  const float* w_up     = (const float*)d_in[19];
  const float* w_down   = (const float*)d_in[20];
  const float* w_lm     = (const float*)d_in[21];

  float* outp    = (float*)d_out;
  float* logits  = outp;                                  // [128][32768]
  float* k_out0  = outp + (size_t)Tm * Vv;                // [12][128][256]
  float* v_out0  = k_out0 + (size_t)12 * Tm * HD;         // [12][256][128]

  char* ws = (char*)d_ws;
  auto alloc = [&](size_t bytes) { char* p = ws; ws += (bytes + 255) & ~(size_t)255; return p; };
  float* h     = (float*)alloc((size_t)Tm * Dm * 4);
  short* xb    = (short*)alloc((size_t)Tm * Dm * 2);
  short* qkvp  = (short*)alloc((size_t)6 * Tm * 1536 * 2);
  short* qa    = (short*)alloc((size_t)4 * Tm * HD * 2);
  float* m_p   = (float*)alloc((size_t)4 * 2 * 8 * 64 * 4);
  float* l_p   = (float*)alloc((size_t)4 * 2 * 8 * 64 * 4);
  short* o_p   = (short*)alloc((size_t)4 * 2 * 8 * 64 * 256 * 2);
  short* ao    = (short*)alloc((size_t)Tm * 1024 * 2);
  short* projp = (short*)alloc((size_t)8 * Tm * Dm * 2);
  short* ffb   = (short*)alloc((size_t)Tm * Fm * 2);
  short* downp = (short*)alloc((size_t)8 * Tm * Dm * 2);

  init_h<<<128, 256, 0, stream>>>(emb, pre_attn, h, xb);

  for (int i = 0; i < 12; i++) {
    const int loc = ((i + 1) % 6 == 0) ? 1 : 0;
    const float* cb = loc ? pe_cosl : pe_cos;
    const float* sb = loc ? pe_sinl : pe_sin;
    float* kout = k_out0 + (size_t)i * Tm * HD;
    float* vout = v_out0 + (size_t)i * HD * Tm;

    gemm_bf16<64, 2, 4, 6, true><<<dim3(24, 6), 256, 0, stream>>>(
        xb, w_qkv + (size_t)i * Dm * 1536, qkvp, Dm, 1536);
    qkv_prep<<<128, 256, 0, stream>>>(qkvp, q_norm + i * HD, k_norm + i * HD,
                                      cb, sb, qa, kout, vout);
    flash_partial<<<dim3(8, 2, 4), 256, 0, stream>>>(
        qa, kv_k + (size_t)i * Cm * HD, kout,
        kv_v + (size_t)i * HD * Cm, vout, m_p, l_p, o_p, loc);
    attn_combine<<<dim3(2, 4), 256, 0, stream>>>(m_p, l_p, o_p, ao);
    gemm_bf16<64, 2, 4, 8, true><<<dim3(18, 8), 256, 0, stream>>>(
        ao, w_out + (size_t)i * 1024 * Dm, projp, 1024, Dm);
    resid_norm<8><<<128, 256, 0, stream>>>(projp, post_attn + i * Dm, h, pre_ff + i * Dm, xb);
    gemm_gateup<<<216, 256, 0, stream>>>(
        xb, w_gate + (size_t)i * Dm * Fm, w_up + (size_t)i * Dm * Fm, ffb);
    gemm_bf16<64, 2, 4, 8, true><<<dim3(18, 8), 256, 0, stream>>>(
        ffb, w_down + (size_t)i * Fm * Dm, downp, Fm, Dm);
    const float* nw = (i < 11) ? (pre_attn + (i + 1) * Dm) : final_w;
    resid_norm<8><<<128, 256, 0, stream>>>(downp, post_ff + i * Dm, h, nw, xb);
  }

  gemm_bf16<64, 2, 4, 1, false><<<dim3(512, 1), 256, 0, stream>>>(
      xb, w_lm, logits, Dm, Vv);
}